// Round 1
// baseline (322.773 us; speedup 1.0000x reference)
//
#include <hip/hip_runtime.h>
#include <math.h>

#define NCAP 10
#define IC   6912
#define NJG  432                  // j-groups (16 j each)
#define NSLOT (NJG * 2)           // part slots (864 = 8 * 108, XCD-swizzlable)
#define JPB  16
#define WPAIRS ((IC * NCAP) / 2)  // 34560 W tile-pairs

typedef __attribute__((ext_vector_type(4))) float f32x4;
typedef __attribute__((ext_vector_type(16))) float f32x16;
typedef __attribute__((ext_vector_type(8))) short bf16x8;

// fp32 -> bf16 RNE
static __device__ inline unsigned short f2bf(float f) {
    unsigned int u = __float_as_uint(f);
    unsigned int r = u + 0x7FFFu + ((u >> 16) & 1u);
    return (unsigned short)(r >> 16);
}

// Prep: UNCHANGED (R5-proven). blocks <1024 transpose W into 16x16 A-tile
// order; blocks >=1024 (one per j) convert x into B-tile order bf16.
// The 32x32x16 sweep consumes these same tiles via a lane permutation.
__global__ __launch_bounds__(256) void prep_kernel(
    const float* __restrict__ x, const float* __restrict__ W,
    unsigned short* __restrict__ w_t, unsigned short* __restrict__ x_t,
    int use_xt)
{
    __shared__ float lds[4 * 1312];
    const int tid  = threadIdx.x;
    const int lane = tid & 63;
    const int wv   = tid >> 6;

    if (blockIdx.x < 1024) {
        float* L0 = lds + wv * 1312;
        const int gw = blockIdx.x * 4 + wv;
        const int lr  = lane & 31;
        const int reg = lane >> 5;
        const int ia  = lr >> 2, oq = lr & 3;
        const int o   = lr & 15, kq2 = lr >> 4;
        const float4* W4 = (const float4*)W;
        int itc = 0;
        for (int p = gw; p < WPAIRS; p += 4096, ++itc) {
            float* L = L0 + (itc & 1) * 656;
            const int tl = p * 2 + reg;          // tile id = j*10 + n
            const int n = tl % 10, j = tl / 10;
            const float4* src = W4 + ((size_t)n * IC + j) * 64;
            float4 a = src[lr];
            float4 c = src[lr + 32];
            *(float4*)&L[reg * 328 + ia * 20 + oq * 4] = a;
            *(float4*)&L[reg * 328 + (ia + 8) * 20 + oq * 4] = c;
            bf16x8 fr;
            #pragma unroll
            for (int t = 0; t < 8; ++t)
                fr[t] = (short)f2bf(L[reg * 328 + (kq2 * 8 + t) * 20 + o]);
            *(bf16x8*)&w_t[(size_t)tl * 256 + lr * 8] = fr;
        }
    } else if (use_xt) {
        const int j  = blockIdx.x - 1024;        // 0..6911
        const int bg = wv;                       // b-group of 16
        if (lane < 32) {
            const int bl = lane & 15, kq = lane >> 4;
            const float* xp = x + ((size_t)(bg * 16 + bl) * IC + j) * 16 + kq * 8;
            float4 x0 = *(const float4*)xp;
            float4 x1 = *(const float4*)(xp + 4);
            bf16x8 fr;
            fr[0] = (short)f2bf(x0.x); fr[1] = (short)f2bf(x0.y);
            fr[2] = (short)f2bf(x0.z); fr[3] = (short)f2bf(x0.w);
            fr[4] = (short)f2bf(x1.x); fr[5] = (short)f2bf(x1.y);
            fr[6] = (short)f2bf(x1.z); fr[7] = (short)f2bf(x1.w);
            *(bf16x8*)&x_t[((size_t)j * 4 + bg) * 256 + lane * 8] = fr;
        }
    }
}

// Routing sweep on 32x32x16 MFMA (K=16 exact: no zero padding, all 64 lanes
// load). Block 256 = 4 waves, all on one bh (32 b's); wave jw owns 4 j's.
// A = W[2 capsules x 16o][16i], B = x[16i][32b]. Per j: 5 MFMAs/pass.
// Lane layouts (derived from R2/R5-proven 16x16x32 by the standard 32-lane
// k-grouping): A[m=lane&31][k=(lane>>5)*8+t], B[k][b=lane&31],
// D col=lane&31(=b), row m=(reg&3)+8*(reg>>2)+4*(lane>>5); m>=16 -> capsule
// 2p+1, o=m&15. Old w_t/x_t tiles are consumed via lane permutation
// lr=(lane&15)|((lane>>5)<<4), tile n = 2p + ((lane>>4)&1) -- each 16-lane
// group still reads 256B contiguous.
__global__ __launch_bounds__(256, 3) void sweep_kernel(
    const float* __restrict__ x, const unsigned short* __restrict__ x_t,
    const unsigned short* __restrict__ w_t, const float* __restrict__ vsum,
    float* __restrict__ part, int iter, int use_xt)
{
    __shared__ float smem[10496];   // vv tile (32x164) in loop; 2 combine bufs after

    const int tid  = threadIdx.x;
    const int lane = tid & 63;
    const int jw   = tid >> 6;
    // bijective XCD swizzle: bh-pair blocks (same jg) land on the same XCD L2
    const int logical = ((int)blockIdx.x & 7) * (NSLOT / 8) + ((int)blockIdx.x >> 3);
    const int bh   = logical & 1;
    const int jg   = logical >> 1;
    const int b_l  = lane & 31;          // b within bh half (D/B column)
    const int h    = lane >> 5;          // k-group
    const int nsel = (lane >> 4) & 1;    // capsule parity within pair
    const int lr   = (lane & 15) | (h << 4);  // lane in old 32-lane tile layout
    const int j0   = jg * JPB + jw * 4;

    if (iter > 0) {
        for (int idx = tid; idx < 5120; idx += 256)
            smem[(idx / 160) * 164 + (idx % 160)] = vsum[bh * 5120 + idx];
    }
    __syncthreads();

    const f32x16 zf = (f32x16){0.f,0.f,0.f,0.f,0.f,0.f,0.f,0.f,
                               0.f,0.f,0.f,0.f,0.f,0.f,0.f,0.f};

    f32x16 sac[5];
    #pragma unroll
    for (int p = 0; p < 5; ++p) sac[p] = zf;

    bf16x8 fw[5], fx, nx;

    // ---- prologue: fragments for j0 ----
    #pragma unroll
    for (int p = 0; p < 5; ++p)
        fw[p] = *(const bf16x8*)&w_t[((size_t)(j0 * NCAP + p * 2 + nsel)) * 256 + lr * 8];
    if (use_xt) {
        fx = *(const bf16x8*)&x_t[((size_t)j0 * 4 + bh * 2 + nsel) * 256 + lr * 8];
    } else {
        const float* xp = x + ((size_t)(bh * 32 + b_l) * IC + j0) * 16 + h * 8;
        float4 x0 = *(const float4*)xp, x1 = *(const float4*)(xp + 4);
        fx[0] = (short)f2bf(x0.x); fx[1] = (short)f2bf(x0.y);
        fx[2] = (short)f2bf(x0.z); fx[3] = (short)f2bf(x0.w);
        fx[4] = (short)f2bf(x1.x); fx[5] = (short)f2bf(x1.y);
        fx[6] = (short)f2bf(x1.z); fx[7] = (short)f2bf(x1.w);
    }

    #pragma unroll
    for (int jt = 0; jt < 4; ++jt) {
        const int j  = j0 + jt;
        const int j1 = j + 1;            // only used when jt < 3

        // prefetch next x fragment early (fw refilled in-place during pass 2)
        if (jt < 3) {
            if (use_xt) {
                nx = *(const bf16x8*)&x_t[((size_t)j1 * 4 + bh * 2 + nsel) * 256 + lr * 8];
            } else {
                const float* xp = x + ((size_t)(bh * 32 + b_l) * IC + j1) * 16 + h * 8;
                float4 x0 = *(const float4*)xp, x1 = *(const float4*)(xp + 4);
                nx[0] = (short)f2bf(x0.x); nx[1] = (short)f2bf(x0.y);
                nx[2] = (short)f2bf(x0.z); nx[3] = (short)f2bf(x0.w);
                nx[4] = (short)f2bf(x1.x); nx[5] = (short)f2bf(x1.y);
                nx[6] = (short)f2bf(x1.z); nx[7] = (short)f2bf(x1.w);
            }
        }

        if (iter > 0) {
            // pass 1: routing logits p[b,n] = sum_o u * vv
            float cc[NCAP];
            const int vb = b_l * 164;
            #pragma unroll
            for (int p = 0; p < 5; ++p) {
                f32x16 u = __builtin_amdgcn_mfma_f32_32x32x16_bf16(fw[p], fx, zf, 0, 0, 0);
                f32x4 v0 = *(const f32x4*)&smem[vb + (2 * p) * 16 + 4 * h];
                f32x4 v1 = *(const f32x4*)&smem[vb + (2 * p) * 16 + 8 + 4 * h];
                f32x4 v2 = *(const f32x4*)&smem[vb + (2 * p + 1) * 16 + 4 * h];
                f32x4 v3 = *(const f32x4*)&smem[vb + (2 * p + 1) * 16 + 8 + 4 * h];
                float plo = u[0] * v0[0] + u[1] * v0[1] + u[2] * v0[2] + u[3] * v0[3]
                          + u[4] * v1[0] + u[5] * v1[1] + u[6] * v1[2] + u[7] * v1[3];
                float phi = u[8]  * v2[0] + u[9]  * v2[1] + u[10] * v2[2] + u[11] * v2[3]
                          + u[12] * v3[0] + u[13] * v3[1] + u[14] * v3[2] + u[15] * v3[3];
                plo += __shfl_xor(plo, 32);   // lanes l, l^32: same b, complementary o
                phi += __shfl_xor(phi, 32);
                cc[2 * p] = plo; cc[2 * p + 1] = phi;
            }
            float ssum = 0.f;
            #pragma unroll
            for (int n = 0; n < NCAP; ++n) { cc[n] = __expf(cc[n]); ssum += cc[n]; }
            const float inv = 1.0f / ssum;
            // pass 2: re-MFMA and accumulate; refill fw in place (frees regs)
            #pragma unroll
            for (int p = 0; p < 5; ++p) {
                f32x16 u = __builtin_amdgcn_mfma_f32_32x32x16_bf16(fw[p], fx, zf, 0, 0, 0);
                const float cl = cc[2 * p] * inv, ch = cc[2 * p + 1] * inv;
                #pragma unroll
                for (int q = 0; q < 8; ++q)  sac[p][q] = fmaf(cl, u[q], sac[p][q]);
                #pragma unroll
                for (int q = 8; q < 16; ++q) sac[p][q] = fmaf(ch, u[q], sac[p][q]);
                if (jt < 3)
                    fw[p] = *(const bf16x8*)&w_t[((size_t)(j1 * NCAP + p * 2 + nsel)) * 256 + lr * 8];
            }
        } else {
            // iter 0: c = softmax(0) = 0.1 uniformly, single pass
            #pragma unroll
            for (int p = 0; p < 5; ++p) {
                f32x16 u = __builtin_amdgcn_mfma_f32_32x32x16_bf16(fw[p], fx, zf, 0, 0, 0);
                #pragma unroll
                for (int q = 0; q < 16; ++q) sac[p][q] = fmaf(0.1f, u[q], sac[p][q]);
                if (jt < 3)
                    fw[p] = *(const bf16x8*)&w_t[((size_t)(j1 * NCAP + p * 2 + nsel)) * 256 + lr * 8];
            }
        }
        if (jt < 3) fx = nx;
    }

    // ---- tree-combine 4 waves in LDS, then coalesced part store ----
    __syncthreads();                     // vv region free
    float* bufA = smem;
    float* bufB = smem + 5248;
    const int r0 = b_l * 164 + 4 * h;    // 164-pad breaks the 160-stride bank wall

    auto st = [&](float* buf) {
        #pragma unroll
        for (int p = 0; p < 5; ++p) {
            *(f32x4*)&buf[r0 + (2 * p) * 16]         = (f32x4){sac[p][0],  sac[p][1],  sac[p][2],  sac[p][3]};
            *(f32x4*)&buf[r0 + (2 * p) * 16 + 8]     = (f32x4){sac[p][4],  sac[p][5],  sac[p][6],  sac[p][7]};
            *(f32x4*)&buf[r0 + (2 * p + 1) * 16]     = (f32x4){sac[p][8],  sac[p][9],  sac[p][10], sac[p][11]};
            *(f32x4*)&buf[r0 + (2 * p + 1) * 16 + 8] = (f32x4){sac[p][12], sac[p][13], sac[p][14], sac[p][15]};
        }
    };
    auto ad = [&](const float* buf) {
        #pragma unroll
        for (int p = 0; p < 5; ++p) {
            f32x4 t0 = *(const f32x4*)&buf[r0 + (2 * p) * 16];
            f32x4 t1 = *(const f32x4*)&buf[r0 + (2 * p) * 16 + 8];
            f32x4 t2 = *(const f32x4*)&buf[r0 + (2 * p + 1) * 16];
            f32x4 t3 = *(const f32x4*)&buf[r0 + (2 * p + 1) * 16 + 8];
            #pragma unroll
            for (int q = 0; q < 4; ++q) {
                sac[p][q]      += t0[q];
                sac[p][4 + q]  += t1[q];
                sac[p][8 + q]  += t2[q];
                sac[p][12 + q] += t3[q];
            }
        }
    };

    if (jw == 1) st(bufA);
    if (jw == 3) st(bufB);
    __syncthreads();
    if (jw == 0) ad(bufA);
    if (jw == 2) ad(bufB);
    __syncthreads();
    if (jw == 2) st(bufA);
    __syncthreads();
    if (jw == 0) { ad(bufA); st(bufB); }
    __syncthreads();

    // block-wide coalesced store of the 20KB slot (1KB per wave per instr)
    float* pp = part + (size_t)logical * 5120;
    #pragma unroll
    for (int c5 = 0; c5 < 5; ++c5) {
        const int g  = c5 * 1024 + tid * 4;
        const int br = g / 160, cr = g % 160;
        *(f32x4*)&pp[g] = *(const f32x4*)&bufB[br * 164 + cr];
    }
}

// Fused reduce (NSLOT slots -> s) + squash + vsum/out. Grid 160 x 1024:
// 16-way k-split (was 4) quarters the serial load chain per thread.
__global__ __launch_bounds__(1024) void reduce_kernel(
    const float* __restrict__ part, float* __restrict__ vsum,
    float* __restrict__ out, int iter)
{
    __shared__ float lds[15 * 64];
    const int tid = threadIdx.x;
    const int gi = tid & 63, rq = tid >> 6;       // rq 0..15
    const int g  = blockIdx.x * 64 + gi;          // 0..10239
    const float* p0 = part + g;                   // slot parity encodes bh
    float acc = 0.f;
    for (int k = rq * 27; k < rq * 27 + 27; ++k)  // 16*27 = 432 slots per bh
        acc += p0[(size_t)k * 10240];
    if (rq > 0) lds[(rq - 1) * 64 + gi] = acc;
    __syncthreads();
    if (rq == 0) {
        #pragma unroll
        for (int r = 0; r < 15; ++r) acc += lds[r * 64 + gi];
        float sq = acc * acc;                     // squash over o = bits 0..3
        sq += __shfl_xor(sq, 1);
        sq += __shfl_xor(sq, 2);
        sq += __shfl_xor(sq, 4);
        sq += __shfl_xor(sq, 8);
        float scale = (sq / (1.f + sq)) / sqrtf(sq + 1e-7f);
        float v = scale * acc;
        if (iter == 2)      out[g] = v;
        else if (iter == 0) vsum[g] = v;
        else                vsum[g] += v;
    }
}

extern "C" void kernel_launch(void* const* d_in, const int* in_sizes, int n_in,
                              void* d_out, int out_size, void* d_ws, size_t ws_size,
                              hipStream_t stream) {
    (void)in_sizes; (void)n_in; (void)out_size;
    const float* x = (const float*)d_in[0];   // [64, 6912, 16]
    const float* W = (const float*)d_in[1];   // [10, 6912, 16, 16]
    float* out = (float*)d_out;               // [64, 10, 16]

    const size_t wt_sh = (size_t)IC * NCAP * 256;   // shorts (35.4 MB)
    const size_t xt_sh = (size_t)IC * 4 * 256;      // shorts (14.2 MB)
    const size_t part_f = (size_t)NSLOT * 5120;     // floats (17.7 MB)
    const size_t need_xt = wt_sh * 2 + xt_sh * 2 + part_f * 4 + 10240 * 4;

    int use_xt = (ws_size >= need_xt) ? 1 : 0;
    unsigned short* w_t = (unsigned short*)d_ws;
    unsigned short* x_t = use_xt ? (w_t + wt_sh) : nullptr;
    float* part = (float*)(use_xt ? (void*)(x_t + xt_sh) : (void*)(w_t + wt_sh));
    float* vsum = part + part_f;

    prep_kernel<<<use_xt ? (1024 + IC) : 1024, 256, 0, stream>>>(x, W, w_t, x_t, use_xt);
    for (int iter = 0; iter < 3; ++iter) {
        sweep_kernel<<<NSLOT, 256, 0, stream>>>(x, x_t, w_t, vsum, part, iter, use_xt);
        reduce_kernel<<<160, 1024, 0, stream>>>(part, vsum, out, iter);
    }
}

// Round 2
// 280.812 us; speedup vs baseline: 1.1494x; 1.1494x over previous
//
#include <hip/hip_runtime.h>
#include <math.h>

#define NCAP 10
#define IC   6912
#define NJG  384                  // j-groups (18 j each)
#define NSLOT (NJG * 2)           // part slots (768 = 8 * 96, XCD-swizzlable)
#define WPAIRS ((IC * NCAP) / 2)  // 34560 W tile-pairs

typedef __attribute__((ext_vector_type(4))) float f32x4;
typedef __attribute__((ext_vector_type(8))) short bf16x8;

// fp32 -> bf16 RNE
static __device__ inline unsigned short f2bf(float f) {
    unsigned int u = __float_as_uint(f);
    unsigned int r = u + 0x7FFFu + ((u >> 16) & 1u);
    return (unsigned short)(r >> 16);
}

// Prep: blocks <1024 transpose W into MFMA A-fragment order (R5-proven body);
// blocks >=1024 (one per j) convert x into B-fragment order bf16.
__global__ __launch_bounds__(256) void prep_kernel(
    const float* __restrict__ x, const float* __restrict__ W,
    unsigned short* __restrict__ w_t, unsigned short* __restrict__ x_t,
    int use_xt)
{
    __shared__ float lds[4 * 1312];
    const int tid  = threadIdx.x;
    const int lane = tid & 63;
    const int wv   = tid >> 6;

    if (blockIdx.x < 1024) {
        float* L0 = lds + wv * 1312;
        const int gw = blockIdx.x * 4 + wv;
        const int lr  = lane & 31;
        const int reg = lane >> 5;
        const int ia  = lr >> 2, oq = lr & 3;
        const int o   = lr & 15, kq2 = lr >> 4;
        const float4* W4 = (const float4*)W;
        int itc = 0;
        for (int p = gw; p < WPAIRS; p += 4096, ++itc) {
            float* L = L0 + (itc & 1) * 656;
            const int tl = p * 2 + reg;          // tile id = j*10 + n
            const int n = tl % 10, j = tl / 10;
            const float4* src = W4 + ((size_t)n * IC + j) * 64;
            float4 a = src[lr];
            float4 c = src[lr + 32];
            *(float4*)&L[reg * 328 + ia * 20 + oq * 4] = a;
            *(float4*)&L[reg * 328 + (ia + 8) * 20 + oq * 4] = c;
            bf16x8 fr;
            #pragma unroll
            for (int t = 0; t < 8; ++t)
                fr[t] = (short)f2bf(L[reg * 328 + (kq2 * 8 + t) * 20 + o]);
            *(bf16x8*)&w_t[(size_t)tl * 256 + lr * 8] = fr;
        }
    } else if (use_xt) {
        const int j  = blockIdx.x - 1024;        // 0..6911
        const int bg = wv;                       // b-group of 16
        if (lane < 32) {
            const int bl = lane & 15, kq = lane >> 4;
            const float* xp = x + ((size_t)(bg * 16 + bl) * IC + j) * 16 + kq * 8;
            float4 x0 = *(const float4*)xp;
            float4 x1 = *(const float4*)(xp + 4);
            bf16x8 fr;
            fr[0] = (short)f2bf(x0.x); fr[1] = (short)f2bf(x0.y);
            fr[2] = (short)f2bf(x0.z); fr[3] = (short)f2bf(x0.w);
            fr[4] = (short)f2bf(x1.x); fr[5] = (short)f2bf(x1.y);
            fr[6] = (short)f2bf(x1.z); fr[7] = (short)f2bf(x1.w);
            *(bf16x8*)&x_t[((size_t)j * 4 + bg) * 256 + lane * 8] = fr;
        }
    }
}

// Routing sweep, two-pass MFMA + explicit double buffer, vv in LDS.
// Block 256 = 4 waves = bg_l(2) x jw(2); covers 32 b's (bh half), 18 j's.
// R0-proven body. Only change: bijective XCD swizzle so the two blocks
// sharing a w_t panel (bh=0/1 of one jg) land on the SAME XCD L2
// (logical pair 2k,2k+1 <- blockIdx b,b+8 with b%8 equal).
// Layouts (R2/R5-proven): A[m=o=lane&15][k=(lane>>4)*8+t], B[k][b=lane&15],
// D col=lane&15(=b) row=(lane>>4)*4+reg(=o); K 16->32 zero-padded via zero
// fragments on lanes>=32 (outputs on ALL lanes are valid).
__global__ __launch_bounds__(256, 3) void sweep_kernel(
    const float* __restrict__ x, const unsigned short* __restrict__ x_t,
    const unsigned short* __restrict__ w_t, const float* __restrict__ vsum,
    float* __restrict__ part, int iter, int use_xt)
{
    __shared__ float smem[32 * 164];      // vv tile during loop; cbuf at end

    const int tid  = threadIdx.x;
    const int lane = tid & 63;
    const int wave = tid >> 6;
    const int bl   = lane & 15;
    const int kq   = lane >> 4;
    const bool act = (lane < 32);
    // XCD swizzle: logical slot; pairs (2k,2k+1) come from blockIdx b,b+8.
    const int logical = ((int)blockIdx.x & 7) * (NSLOT / 8) + ((int)blockIdx.x >> 3);
    const int bh   = logical & 1;
    const int jg   = logical >> 1;
    const int bg_l = wave & 1;
    const int jw   = wave >> 1;
    const int b    = bh * 32 + bg_l * 16 + bl;
    const int j0   = jg * 18 + jw * 9;
    const int vrow = (bg_l * 16 + bl) * 164;

    const f32x4 zf = (f32x4){0.f, 0.f, 0.f, 0.f};
    const bf16x8 zb = (bf16x8){0, 0, 0, 0, 0, 0, 0, 0};

    if (iter > 0) {
        for (int idx = tid; idx < 5120; idx += 256)
            smem[(idx / 160) * 164 + (idx % 160)] = vsum[bh * 5120 + idx];
    }
    __syncthreads();

    f32x4 sac[NCAP];
    #pragma unroll
    for (int n = 0; n < NCAP; ++n) sac[n] = zf;

    // ---- load fragments for j0 ----
    bf16x8 fw[NCAP]; bf16x8 fx;
    fx = zb;
    #pragma unroll
    for (int n = 0; n < NCAP; ++n) fw[n] = zb;
    if (act) {
        if (use_xt) {
            fx = *(const bf16x8*)&x_t[((size_t)j0 * 4 + bh * 2 + bg_l) * 256 + lane * 8];
        } else {
            const float* xp = x + ((size_t)b * IC + j0) * 16 + kq * 8;
            float4 x0 = *(const float4*)xp, x1 = *(const float4*)(xp + 4);
            fx[0] = (short)f2bf(x0.x); fx[1] = (short)f2bf(x0.y);
            fx[2] = (short)f2bf(x0.z); fx[3] = (short)f2bf(x0.w);
            fx[4] = (short)f2bf(x1.x); fx[5] = (short)f2bf(x1.y);
            fx[6] = (short)f2bf(x1.z); fx[7] = (short)f2bf(x1.w);
        }
        #pragma unroll
        for (int n = 0; n < NCAP; ++n)
            fw[n] = *(const bf16x8*)&w_t[((size_t)j0 * NCAP + n) * 256 + lane * 8];
    }

    #pragma unroll
    for (int jt = 0; jt < 9; ++jt) {
        // ---- prefetch j+1 ----
        bf16x8 nw_[NCAP]; bf16x8 nx;
        nx = zb;
        #pragma unroll
        for (int n = 0; n < NCAP; ++n) nw_[n] = zb;
        if (jt < 8) {
            const int j1 = j0 + jt + 1;
            if (act) {
                if (use_xt) {
                    nx = *(const bf16x8*)&x_t[((size_t)j1 * 4 + bh * 2 + bg_l) * 256 + lane * 8];
                } else {
                    const float* xp = x + ((size_t)b * IC + j1) * 16 + kq * 8;
                    float4 x0 = *(const float4*)xp, x1 = *(const float4*)(xp + 4);
                    nx[0] = (short)f2bf(x0.x); nx[1] = (short)f2bf(x0.y);
                    nx[2] = (short)f2bf(x0.z); nx[3] = (short)f2bf(x0.w);
                    nx[4] = (short)f2bf(x1.x); nx[5] = (short)f2bf(x1.y);
                    nx[6] = (short)f2bf(x1.z); nx[7] = (short)f2bf(x1.w);
                }
                #pragma unroll
                for (int n = 0; n < NCAP; ++n)
                    nw_[n] = *(const bf16x8*)&w_t[((size_t)j1 * NCAP + n) * 256 + lane * 8];
            }
        }

        // ---- compute on current j ----
        if (iter == 0) {
            #pragma unroll
            for (int n = 0; n < NCAP; ++n) {
                f32x4 u4 = __builtin_amdgcn_mfma_f32_16x16x32_bf16(fw[n], fx, zf, 0, 0, 0);
                sac[n][0] = fmaf(0.1f, u4[0], sac[n][0]);
                sac[n][1] = fmaf(0.1f, u4[1], sac[n][1]);
                sac[n][2] = fmaf(0.1f, u4[2], sac[n][2]);
                sac[n][3] = fmaf(0.1f, u4[3], sac[n][3]);
            }
        } else {
            // pass 1: routing logits (u transient)
            float bb_[NCAP];
            #pragma unroll
            for (int n = 0; n < NCAP; ++n) {
                f32x4 u4 = __builtin_amdgcn_mfma_f32_16x16x32_bf16(fw[n], fx, zf, 0, 0, 0);
                f32x4 vvn = *(const f32x4*)&smem[vrow + n * 16 + kq * 4];
                float p = u4[0] * vvn[0] + u4[1] * vvn[1]
                        + u4[2] * vvn[2] + u4[3] * vvn[3];
                p += __shfl_xor(p, 16);
                p += __shfl_xor(p, 32);
                bb_[n] = p;
            }
            float ssum = 0.f;
            float c[NCAP];
            #pragma unroll
            for (int n = 0; n < NCAP; ++n) { c[n] = __expf(bb_[n]); ssum += c[n]; }
            const float inv = 1.0f / ssum;
            // pass 2: re-MFMA and accumulate
            #pragma unroll
            for (int n = 0; n < NCAP; ++n) {
                f32x4 u4 = __builtin_amdgcn_mfma_f32_16x16x32_bf16(fw[n], fx, zf, 0, 0, 0);
                const float cn = c[n] * inv;
                sac[n][0] = fmaf(cn, u4[0], sac[n][0]);
                sac[n][1] = fmaf(cn, u4[1], sac[n][1]);
                sac[n][2] = fmaf(cn, u4[2], sac[n][2]);
                sac[n][3] = fmaf(cn, u4[3], sac[n][3]);
            }
        }

        // rotate buffers (vanishes under full unroll)
        fx = nx;
        #pragma unroll
        for (int n = 0; n < NCAP; ++n) fw[n] = nw_[n];
    }

    // ---- combine jw=1 into jw=0 and store partial ----
    __syncthreads();                       // everyone done reading vv region
    const int sb = (bg_l * 16 + bl) * 164 + kq * 4;
    if (jw == 1) {
        #pragma unroll
        for (int n = 0; n < NCAP; ++n)
            *(f32x4*)&smem[sb + n * 16] = sac[n];
    }
    __syncthreads();
    if (jw == 0) {
        float* pp = part + (size_t)logical * 5120;
        #pragma unroll
        for (int n = 0; n < NCAP; ++n) {
            f32x4 t = *(const f32x4*)&smem[sb + n * 16];
            t[0] += sac[n][0]; t[1] += sac[n][1];
            t[2] += sac[n][2]; t[3] += sac[n][3];
            *(f32x4*)&pp[(bg_l * 16 + bl) * 160 + n * 16 + kq * 4] = t;
        }
    }
}

// Fused reduce (NSLOT slots -> s) + squash + vsum/out. Grid 160 x 1024:
// 16-way k-split quarters the serial load chain per thread vs the 4-way R0.
// part is laid out by logical slot; pairs (jg: bh0,bh1) are contiguous
// 10240-float super-slots, so p0 = part + g with stride 10240 covers all.
__global__ __launch_bounds__(1024) void reduce_kernel(
    const float* __restrict__ part, float* __restrict__ vsum,
    float* __restrict__ out, int iter)
{
    __shared__ float lds[15 * 64];
    const int tid = threadIdx.x;
    const int gi = tid & 63, rq = tid >> 6;       // rq 0..15
    const int g  = blockIdx.x * 64 + gi;          // 0..10239
    const float* p0 = part + g;                   // slot parity encodes bh
    float acc = 0.f;
    for (int k = rq * 24; k < rq * 24 + 24; ++k)  // 16*24 = 384 jg pairs
        acc += p0[(size_t)k * 10240];
    if (rq > 0) lds[(rq - 1) * 64 + gi] = acc;
    __syncthreads();
    if (rq == 0) {
        #pragma unroll
        for (int r = 0; r < 15; ++r) acc += lds[r * 64 + gi];
        float sq = acc * acc;                     // squash over o = bits 0..3
        sq += __shfl_xor(sq, 1);
        sq += __shfl_xor(sq, 2);
        sq += __shfl_xor(sq, 4);
        sq += __shfl_xor(sq, 8);
        float scale = (sq / (1.f + sq)) / sqrtf(sq + 1e-7f);
        float v = scale * acc;
        if (iter == 2)      out[g] = v;
        else if (iter == 0) vsum[g] = v;
        else                vsum[g] += v;
    }
}

extern "C" void kernel_launch(void* const* d_in, const int* in_sizes, int n_in,
                              void* d_out, int out_size, void* d_ws, size_t ws_size,
                              hipStream_t stream) {
    (void)in_sizes; (void)n_in; (void)out_size;
    const float* x = (const float*)d_in[0];   // [64, 6912, 16]
    const float* W = (const float*)d_in[1];   // [10, 6912, 16, 16]
    float* out = (float*)d_out;               // [64, 10, 16]

    const size_t wt_sh = (size_t)IC * NCAP * 256;   // shorts (35.4 MB)
    const size_t xt_sh = (size_t)IC * 4 * 256;      // shorts (14.2 MB)
    const size_t part_f = (size_t)NSLOT * 5120;     // floats (15.7 MB)
    const size_t need_xt = wt_sh * 2 + xt_sh * 2 + part_f * 4 + 10240 * 4;

    int use_xt = (ws_size >= need_xt) ? 1 : 0;
    unsigned short* w_t = (unsigned short*)d_ws;
    unsigned short* x_t = use_xt ? (w_t + wt_sh) : nullptr;
    float* part = (float*)(use_xt ? (void*)(x_t + xt_sh) : (void*)(w_t + wt_sh));
    float* vsum = part + part_f;

    prep_kernel<<<use_xt ? (1024 + IC) : 1024, 256, 0, stream>>>(x, W, w_t, x_t, use_xt);
    for (int iter = 0; iter < 3; ++iter) {
        sweep_kernel<<<NSLOT, 256, 0, stream>>>(x, x_t, w_t, vsum, part, iter, use_xt);
        reduce_kernel<<<160, 1024, 0, stream>>>(part, vsum, out, iter);
    }
}